// Round 17
// baseline (485.686 us; speedup 1.0000x reference)
//
#include <hip/hip_runtime.h>
#include <hip/hip_bf16.h>
#include <cstdint>
#include <cstddef>

// Problem dims (fixed)
constexpr int cB   = 64;
constexpr int cC   = 384;
constexpr int cH   = 28;
constexpr int cW   = 28;
constexpr int cHW  = cH * cW;         // 784
constexpr int cHID = 1536;
constexpr int cNTOK = cB * cH * cW;   // 50176
constexpr int cKP   = cHID + 32;      // h row: 1536 fc1 cols + 32 lora-z cols = 1568
constexpr int cCH   = 2;              // M chunks
constexpr int cMR   = cNTOK / cCH;    // 25088

typedef __attribute__((ext_vector_type(8))) short bf16x8;
typedef __attribute__((ext_vector_type(4))) float f32x4;

__device__ __forceinline__ float gelu_f(float x) {
  float u = 1.5957691216057308f * x * (1.0f + 0.044715f * x * x);
  float e = __expf(-u);
  return x / (1.0f + e);
}

__device__ __forceinline__ float bf16_to_f(unsigned short s) {
  return __uint_as_float(((unsigned)s) << 16);
}
__device__ __forceinline__ unsigned short f_to_bf16(float v) {
  __hip_bfloat16 hb = __float2bfloat16(v);
  return *reinterpret_cast<unsigned short*>(&hb);
}

__device__ __forceinline__ void gload_lds16(const void* g, void* l) {
  __builtin_amdgcn_global_load_lds(
      (const __attribute__((address_space(1))) unsigned int*)g,
      (__attribute__((address_space(3))) unsigned int*)l, 16, 0, 0);
}

// T1: bijective XCD-chunked block remap (m204).
__device__ __forceinline__ int xcd_remap(int b, int nwg) {
  int qn = nwg >> 3, rm = nwg & 7;
  int xcd = b & 7, off = b >> 3;
  return (xcd < rm) ? xcd * (qn + 1) + off
                    : rm * (qn + 1) + (xcd - rm) * qn + off;
}

// ---------------------------------------------------------------- prep ----
__global__ __launch_bounds__(256) void prep_eff(
    const float* __restrict__ ng, const float* __restrict__ nb,
    const float* __restrict__ dg, const float* __restrict__ db,
    const float* __restrict__ rw, float* __restrict__ geff, float* __restrict__ beff) {
  int i = blockIdx.x * 256 + threadIdx.x;  // b*C + c
  if (i >= cB * cC) return;
  int b = i / cC, c = i - b * cC;
  float g = ng[c], bb = nb[c];
#pragma unroll
  for (int e = 0; e < 3; ++e) {
    float r = rw[b * 3 + e];
    g += r * dg[e * cC + c];
    bb += r * db[e * cC + c];
  }
  geff[i] = g;
  beff[i] = bb;
}

// fc1_w [C][HID] f32 -> fc1t [HID][C] bf16, LDS-tiled 64x64.
__global__ __launch_bounds__(256) void transpose_bf16(
    const float* __restrict__ w, __hip_bfloat16* __restrict__ wt, int R0, int C0) {
  __shared__ float t[64][65];
  int c0 = blockIdx.x * 64, r0 = blockIdx.y * 64;
  for (int i = threadIdx.x; i < 64 * 64; i += 256) {
    int r = i >> 6, c = i & 63;
    t[r][c] = w[(size_t)(r0 + r) * C0 + c0 + c];
  }
  __syncthreads();
  for (int i = threadIdx.x; i < 64 * 64; i += 256) {
    int c = i >> 6, r = i & 63;
    wt[(size_t)(c0 + c) * R0 + r0 + r] = __float2bfloat16(t[r][c]);
  }
}

// fc2t [C=384][KP=1568]: k<1536 -> fc2_w[k][c]; 1536+j (j<24) -> wu[e][r][c]; else 0
__global__ __launch_bounds__(256) void build_fc2t(
    const float* __restrict__ fc2w, const float* __restrict__ wu,
    __hip_bfloat16* __restrict__ fc2t) {
  int i = blockIdx.x * 256 + threadIdx.x;  // c*KP + k
  if (i >= cC * cKP) return;
  int c = i / cKP, k = i - c * cKP;
  float v = 0.f;
  if (k < cHID) v = fc2w[(size_t)k * cC + c];
  else {
    int j = k - cHID;
    if (j < 24) v = wu[(size_t)(j >> 3) * 8 * cC + (size_t)(j & 7) * cC + c];
  }
  fc2t[i] = __float2bfloat16(v);
}

// wdt [32][C=384]
__global__ __launch_bounds__(256) void build_wdt(
    const float* __restrict__ wd, __hip_bfloat16* __restrict__ wdt) {
  int i = blockIdx.x * 256 + threadIdx.x;  // j*C + c
  if (i >= 32 * cC) return;
  int j = i / cC, c = i - j * cC;
  float v = 0.f;
  if (j < 24) v = wd[(size_t)(j >> 3) * cC * 8 + (size_t)c * 8 + (j & 7)];
  wdt[i] = __float2bfloat16(v);
}

// ---------------------------------------------------- depthwise conv ----
// r10's proven config: 4 planes, 128 threads, 21.5KB LDS, stride-38 rows.
constexpr int cPL = 4;
__global__ __launch_bounds__(128) void conv_dw(
    const float* __restrict__ x, const float* __restrict__ cw,
    const float* __restrict__ cb, __hip_bfloat16* __restrict__ out) {
  int pb = blockIdx.x * cPL;
  int c0 = pb % cC;
  __shared__ __align__(16) float tile[cPL][34][38];
  __shared__ float wsm[cPL][49];
  const int tid = threadIdx.x;

  float2 z2 = {0.f, 0.f};
  for (int i = tid; i < cPL * 34 * 19; i += 128)
    ((float2*)tile)[i] = z2;
  __syncthreads();

  for (int i = tid; i < cPL * 196; i += 128) {
    int p = i / 196, q = i - p * 196;
    int r = q / 7, cl = (q - r * 7) * 4;
    float4 v = *(const float4*)&x[(size_t)(pb + p) * 784 + r * 28 + cl];
    float* dst = &tile[p][r + 3][cl + 4];
    *(float2*)dst = make_float2(v.x, v.y);
    *(float2*)(dst + 2) = make_float2(v.z, v.w);
  }
  for (int i = tid; i < cPL * 49; i += 128) {
    int p = i / 49, k = i - p * 49;
    wsm[p][k] = cw[(size_t)(c0 + p) * 49 + k];
  }
  __syncthreads();

  if (tid < cPL * 28) {
    int p = tid / 28, r = tid - p * 28;
    float acc[28];
    float cbv = cb[c0 + p];
#pragma unroll
    for (int w = 0; w < 28; ++w) acc[w] = cbv;
    for (int dh = 0; dh < 7; ++dh) {
      float rowv[36];
      const float* rp = &tile[p][r + dh][0];
#pragma unroll
      for (int k = 0; k < 18; ++k)
        ((float2*)rowv)[k] = *(const float2*)(rp + k * 2);
      float w7[7];
#pragma unroll
      for (int dw = 0; dw < 7; ++dw) w7[dw] = wsm[p][dh * 7 + dw];
#pragma unroll
      for (int w = 0; w < 28; ++w)
#pragma unroll
        for (int dw = 0; dw < 7; ++dw)
          acc[w] += rowv[w + dw + 1] * w7[dw];
    }
    unsigned short* op = (unsigned short*)out + (size_t)(pb + p) * 784 + r * 28;
#pragma unroll
    for (int k = 0; k < 7; ++k) {
      ushort4 s;
      s.x = f_to_bf16(acc[k * 4 + 0]);
      s.y = f_to_bf16(acc[k * 4 + 1]);
      s.z = f_to_bf16(acc[k * 4 + 2]);
      s.w = f_to_bf16(acc[k * 4 + 3]);
      *(ushort4*)&op[k * 4] = s;
    }
  }
}

// ------------------------------------------- LayerNorm + affine -> bf16 ----
__global__ __launch_bounds__(256) void ln_affine(
    const __hip_bfloat16* __restrict__ convout, const float* __restrict__ geff,
    const float* __restrict__ beff, __hip_bfloat16* __restrict__ y) {
  int bh = blockIdx.x;
  int b = bh / cH;
  int hrow = bh - b * cH;
  __shared__ float t[cC * 29];
  const unsigned short* src =
      (const unsigned short*)convout + (size_t)b * cC * cHW + (size_t)hrow * cW;
  for (int i = threadIdx.x; i < cC * 7; i += 256) {
    int c = i / 7, wq = (i - c * 7) * 4;
    ushort4 v = *(const ushort4*)&src[(size_t)c * cHW + wq];
    t[c * 29 + wq + 0] = bf16_to_f(v.x);
    t[c * 29 + wq + 1] = bf16_to_f(v.y);
    t[c * 29 + wq + 2] = bf16_to_f(v.z);
    t[c * 29 + wq + 3] = bf16_to_f(v.w);
  }
  __syncthreads();
  int wave = threadIdx.x >> 6, lane = threadIdx.x & 63;
  const float* gp = geff + (size_t)b * cC;
  const float* bp = beff + (size_t)b * cC;
  for (int w = wave; w < cW; w += 4) {
    float v[6], s = 0.f, s2 = 0.f;
#pragma unroll
    for (int j = 0; j < 6; ++j) {
      v[j] = t[(lane + 64 * j) * 29 + w];
      s += v[j];
      s2 += v[j] * v[j];
    }
#pragma unroll
    for (int d = 32; d; d >>= 1) {
      s += __shfl_xor(s, d);
      s2 += __shfl_xor(s2, d);
    }
    float mu = s * (1.0f / cC);
    float var = s2 * (1.0f / cC) - mu * mu;
    float rstd = rsqrtf(var + 1e-6f);
    size_t n = (size_t)bh * cW + w;
#pragma unroll
    for (int j = 0; j < 6; ++j) {
      int c = lane + 64 * j;
      float val = (v[j] - mu) * rstd * gp[c] + bp[c];
      y[n * cC + c] = __float2bfloat16(val);
    }
  }
}

// ------------------------------------------------------------ GEMM fc1 ----
// SWAPPED operands: M=HID (fc1t rows), N=tokens (y rows). acc quads = 4
// consecutive hid values for one token -> h[token][hid..hid+3] is ONE 8B
// store (vs 64 scattered 2B stores in row-major orientation).
// Loop body is r10's wall-best: BK=32, 4 waves 2x2, 2-deep dbuf, linear LDS.
__global__ __launch_bounds__(256) void gemm_fc1(
    const __hip_bfloat16* __restrict__ Wt,   // fc1t [HID][C]
    const __hip_bfloat16* __restrict__ Y,    // y chunk [MR][C]
    const float* __restrict__ bias,          // fc1_b [HID]
    __hip_bfloat16* __restrict__ h) {        // h chunk [MR][KP]
  __shared__ __align__(16) __hip_bfloat16 As[2][128 * 32];
  __shared__ __align__(16) __hip_bfloat16 Bs[2][128 * 32];
  const int NT_N = cMR / 128;  // 196
  const int bid = xcd_remap(blockIdx.x, gridDim.x);
  const int gsz = 8 * NT_N;
  const int g = bid / gsz;
  const int q = bid - g * gsz;
  const int mi = g * 8 + q / NT_N;
  const int ni = q - (q / NT_N) * NT_N;
  const int m0 = mi * 128, n0 = ni * 128;   // m0: hid, n0: token

  const int tid = threadIdx.x;
  const int lane = tid & 63;
  const int wid = tid >> 6;
  const int wm = wid >> 1, wn = wid & 1;
  const int l15 = lane & 15, lq = lane >> 4;

  const int base0 = wid * 2048;
  const int base1 = base0 + 1024;
  const int off0 = base0 + lane * 16, off1 = base1 + lane * 16;
  const int row0 = off0 >> 6, col0 = (off0 >> 1) & 31;
  const int row1 = off1 >> 6, col1 = (off1 >> 1) & 31;
  const __hip_bfloat16* pa0 = &Wt[(size_t)(m0 + row0) * cC + col0];
  const __hip_bfloat16* pa1 = &Wt[(size_t)(m0 + row1) * cC + col1];
  const __hip_bfloat16* pb0 = &Y[(size_t)(n0 + row0) * cC + col0];
  const __hip_bfloat16* pb1 = &Y[(size_t)(n0 + row1) * cC + col1];

  const int nt = cC >> 5;  // 12

  gload_lds16(pa0, (char*)As[0] + base0);
  gload_lds16(pa1, (char*)As[0] + base1);
  gload_lds16(pb0, (char*)Bs[0] + base0);
  gload_lds16(pb1, (char*)Bs[0] + base1);
  pa0 += 32; pa1 += 32; pb0 += 32; pb1 += 32;
  __syncthreads();

  f32x4 acc[4][4] = {};
  int cur = 0;
  for (int t = 0; t < nt; ++t, cur ^= 1) {
    if (t + 1 < nt) {
      gload_lds16(pa0, (char*)As[cur ^ 1] + base0);
      gload_lds16(pa1, (char*)As[cur ^ 1] + base1);
      gload_lds16(pb0, (char*)Bs[cur ^ 1] + base0);
      gload_lds16(pb1, (char*)Bs[cur ^ 1] + base1);
      pa0 += 32; pa1 += 32; pb0 += 32; pb1 += 32;
    }
    bf16x8 af[4], bf[4];
#pragma unroll
    for (int i = 0; i < 4; ++i)
      af[i] = *(const bf16x8*)&As[cur][(wm * 64 + i * 16 + l15) * 32 + lq * 8];
#pragma unroll
    for (int i = 0; i < 4; ++i)
      bf[i] = *(const bf16x8*)&Bs[cur][(wn * 64 + i * 16 + l15) * 32 + lq * 8];
#pragma unroll
    for (int i = 0; i < 4; ++i)
#pragma unroll
      for (int j = 0; j < 4; ++j)
        acc[i][j] = __builtin_amdgcn_mfma_f32_16x16x32_bf16(af[i], bf[j], acc[i][j], 0, 0, 0);
    __syncthreads();
  }

  // epilogue: quad = 4 consecutive hid for one token -> 8B stores
#pragma unroll
  for (int i = 0; i < 4; ++i) {
    int hid = m0 + wm * 64 + i * 16 + lq * 4;
    float4 bv = *(const float4*)&bias[hid];
#pragma unroll
    for (int j = 0; j < 4; ++j) {
      int tok = n0 + wn * 64 + j * 16 + l15;
      ushort4 s;
      s.x = f_to_bf16(gelu_f(acc[i][j][0] + bv.x));
      s.y = f_to_bf16(gelu_f(acc[i][j][1] + bv.y));
      s.z = f_to_bf16(gelu_f(acc[i][j][2] + bv.z));
      s.w = f_to_bf16(gelu_f(acc[i][j][3] + bv.w));
      *(ushort4*)&h[(size_t)tok * cKP + hid] = s;
    }
  }
}

// --------------------------------------------------- GEMM fc2 + residual ----
// M=tokens, N=C. acc quad = 4 consecutive tokens at one channel c ->
// out[(b*C+c)*784 + hw..hw+3] is ONE float4 (token quads never cross b since
// 784%4==0). Fuses bias + gamma + residual: kills tmpb and final_out.
__global__ __launch_bounds__(256) void gemm_fc2o(
    const __hip_bfloat16* __restrict__ Hc,   // h chunk [MR][KP]
    const __hip_bfloat16* __restrict__ Bt,   // fc2t [C][KP]
    const float* __restrict__ bias,          // fc2_b [C]
    const float* __restrict__ gamma,         // [C]
    const float* __restrict__ x,             // [B][C][784]
    float* __restrict__ out,                 // [B][C][784]
    int tok0) {                              // chunk token offset
  __shared__ __align__(16) __hip_bfloat16 As[2][128 * 32];
  __shared__ __align__(16) __hip_bfloat16 Bs[2][128 * 32];
  const int NT_N = cC / 128;  // 3
  const int bid = xcd_remap(blockIdx.x, gridDim.x);
  const int gsz = 8 * NT_N;
  const int g = bid / gsz;
  const int q = bid - g * gsz;
  const int mi = g * 8 + q / NT_N;
  const int ni = q - (q / NT_N) * NT_N;
  const int m0 = mi * 128, n0 = ni * 128;   // m0: token, n0: channel

  const int tid = threadIdx.x;
  const int lane = tid & 63;
  const int wid = tid >> 6;
  const int wm = wid >> 1, wn = wid & 1;
  const int l15 = lane & 15, lq = lane >> 4;

  const int base0 = wid * 2048;
  const int base1 = base0 + 1024;
  const int off0 = base0 + lane * 16, off1 = base1 + lane * 16;
  const int row0 = off0 >> 6, col0 = (off0 >> 1) & 31;
  const int row1 = off1 >> 6, col1 = (off1 >> 1) & 31;
  const __hip_bfloat16* pa0 = &Hc[(size_t)(m0 + row0) * cKP + col0];
  const __hip_bfloat16* pa1 = &Hc[(size_t)(m0 + row1) * cKP + col1];
  const __hip_bfloat16* pb0 = &Bt[(size_t)(n0 + row0) * cKP + col0];
  const __hip_bfloat16* pb1 = &Bt[(size_t)(n0 + row1) * cKP + col1];

  const int nt = cKP >> 5;  // 49

  gload_lds16(pa0, (char*)As[0] + base0);
  gload_lds16(pa1, (char*)As[0] + base1);
  gload_lds16(pb0, (char*)Bs[0] + base0);
  gload_lds16(pb1, (char*)Bs[0] + base1);
  pa0 += 32; pa1 += 32; pb0 += 32; pb1 += 32;
  __syncthreads();

  f32x4 acc[4][4] = {};
  int cur = 0;
  for (int t = 0; t < nt; ++t, cur ^= 1) {
    if (t + 1 < nt) {
      gload_lds16(pa0, (char*)As[cur ^ 1] + base0);
      gload_lds16(pa1, (char*)As[cur ^ 1] + base1);
      gload_lds16(pb0, (char*)Bs[cur ^ 1] + base0);
      gload_lds16(pb1, (char*)Bs[cur ^ 1] + base1);
      pa0 += 32; pa1 += 32; pb0 += 32; pb1 += 32;
    }
    bf16x8 af[4], bf[4];
#pragma unroll
    for (int i = 0; i < 4; ++i)
      af[i] = *(const bf16x8*)&As[cur][(wm * 64 + i * 16 + l15) * 32 + lq * 8];
#pragma unroll
    for (int i = 0; i < 4; ++i)
      bf[i] = *(const bf16x8*)&Bs[cur][(wn * 64 + i * 16 + l15) * 32 + lq * 8];
#pragma unroll
    for (int i = 0; i < 4; ++i)
#pragma unroll
      for (int j = 0; j < 4; ++j)
        acc[i][j] = __builtin_amdgcn_mfma_f32_16x16x32_bf16(af[i], bf[j], acc[i][j], 0, 0, 0);
    __syncthreads();
  }

  // epilogue: quad = 4 consecutive tokens at channel c -> float4 out+res
#pragma unroll
  for (int i = 0; i < 4; ++i) {
    int tok = tok0 + m0 + wm * 64 + i * 16 + lq * 4;  // multiple of 4
    int b = tok / cHW;
    int hw = tok - b * cHW;                           // mult of 4, <= 780
#pragma unroll
    for (int j = 0; j < 4; ++j) {
      int c = n0 + wn * 64 + j * 16 + l15;
      float bv = bias[c], ga = gamma[c];
      size_t o = ((size_t)b * cC + c) * cHW + hw;
      float4 xr = *(const float4*)&x[o];
      float4 ov;
      ov.x = ga * (acc[i][j][0] + bv) + xr.x;
      ov.y = ga * (acc[i][j][1] + bv) + xr.y;
      ov.z = ga * (acc[i][j][2] + bv) + xr.z;
      ov.w = ga * (acc[i][j][3] + bv) + xr.w;
      *(float4*)&out[o] = ov;
    }
  }
}

// ----------------------------------------------------------- LoRA down ----
__global__ __launch_bounds__(256) void lora_down(
    const __hip_bfloat16* __restrict__ y,    // chunk base [MR][384]
    const __hip_bfloat16* __restrict__ wdt,  // [32][384]
    const float* __restrict__ probs,         // chunk base [MR][2]
    const int* __restrict__ inds,            // chunk base [MR][2]
    __hip_bfloat16* __restrict__ h) {        // chunk base [MR][cKP]
  __shared__ __align__(16) __hip_bfloat16 As[2][128 * 32];
  __shared__ __align__(16) __hip_bfloat16 Bsm[32 * 384];
  const int tid = threadIdx.x, lane = tid & 63, wid = tid >> 6;
  const int n0 = blockIdx.x * 128;

  for (int i = tid; i < 32 * 384 / 8; i += 256)
    ((bf16x8*)Bsm)[i] = ((const bf16x8*)wdt)[i];

  const int base0 = wid * 2048, base1 = base0 + 1024;
  const int off0 = base0 + lane * 16, off1 = base1 + lane * 16;
  const int row0 = off0 >> 6, col0 = (off0 >> 1) & 31;
  const int row1 = off1 >> 6, col1 = (off1 >> 1) & 31;
  const __hip_bfloat16* pa0 = &y[(size_t)(n0 + row0) * cC + col0];
  const __hip_bfloat16* pa1 = &y[(size_t)(n0 + row1) * cC + col1];

  const int nt = cC >> 5;  // 12
  gload_lds16(pa0, (char*)As[0] + base0);
  gload_lds16(pa1, (char*)As[0] + base1);
  pa0 += 32; pa1 += 32;
  __syncthreads();

  f32x4 acc[2][2] = {};
  int cur = 0;
  for (int t = 0; t < nt; ++t, cur ^= 1) {
    if (t + 1 < nt) {
      gload_lds16(pa0, (char*)As[cur ^ 1] + base0);
      gload_lds16(pa1, (char*)As[cur ^ 1] + base1);
      pa0 += 32; pa1 += 32;
    }
    int kt = t * 32;
    bf16x8 af[2], bfr[2];
#pragma unroll
    for (int i = 0; i < 2; ++i)
      af[i] = *(const bf16x8*)&As[cur][(wid * 32 + i * 16 + (lane & 15)) * 32 + (lane >> 4) * 8];
#pragma unroll
    for (int j = 0; j < 2; ++j)
      bfr[j] = *(const bf16x8*)&Bsm[(j * 16 + (lane & 15)) * 384 + kt + (lane >> 4) * 8];
#pragma unroll
    for (int i = 0; i < 2; ++i)
#pragma unroll
      for (int j = 0; j < 2; ++j)
        acc[i][j] = __builtin_amdgcn_mfma_f32_16x16x32_bf16(af[i], bfr[j], acc[i][j], 0, 0, 0);
    __syncthreads();
  }

#pragma unroll
  for (int i = 0; i < 2; ++i) {
#pragma unroll
    for (int j = 0; j < 2; ++j) {
      int colb = j * 16 + (lane & 15);
#pragma unroll
      for (int r = 0; r < 4; ++r) {
        int n = n0 + wid * 32 + i * 16 + (lane >> 4) * 4 + r;
        float zv = 0.f;
        if (colb < 24) {
          int e = colb >> 3;
          float comb = 0.f;
          if (inds[(size_t)n * 2] == e)     comb += probs[(size_t)n * 2];
          if (inds[(size_t)n * 2 + 1] == e) comb += probs[(size_t)n * 2 + 1];
          zv = comb * gelu_f(acc[i][j][r]);
        }
        h[(size_t)n * cKP + cHID + colb] = __float2bfloat16(zv);
      }
    }
  }
}

// ---------------------------------------------------------------------------
extern "C" void kernel_launch(void* const* d_in, const int* in_sizes, int n_in,
                              void* d_out, int out_size, void* d_ws, size_t ws_size,
                              hipStream_t stream) {
  const float* x      = (const float*)d_in[0];
  const float* conv_w = (const float*)d_in[1];
  const float* conv_b = (const float*)d_in[2];
  const float* norm_g = (const float*)d_in[3];
  const float* norm_b = (const float*)d_in[4];
  const float* dom_g  = (const float*)d_in[5];
  const float* dom_b  = (const float*)d_in[6];
  const float* fc1_w  = (const float*)d_in[7];
  const float* fc1_b  = (const float*)d_in[8];
  const float* fc2_w  = (const float*)d_in[9];
  const float* fc2_b  = (const float*)d_in[10];
  const float* w_down = (const float*)d_in[11];
  const float* w_up   = (const float*)d_in[12];
  const float* gamma  = (const float*)d_in[13];
  const float* rw     = (const float*)d_in[14];
  const float* tkp    = (const float*)d_in[15];
  const int*   tki    = (const int*)d_in[16];
  float* out = (float*)d_out;

  // ws layout (bytes): total ~119.8 MB
  char* ws = (char*)d_ws;
  __hip_bfloat16* y      = (__hip_bfloat16*)(ws + 0);             // 38,535,168
  char*           hslot  = ws + 38535168;                         // 78,675,968
  __hip_bfloat16* h      = (__hip_bfloat16*)hslot;                // [MR][1568]
  __hip_bfloat16* convb  = (__hip_bfloat16*)hslot;                // conv buf (bf16)
  __hip_bfloat16* fc1t   = (__hip_bfloat16*)(ws + 117211136);     // 1,179,648
  __hip_bfloat16* fc2t   = (__hip_bfloat16*)(ws + 118390784);     // 1,204,224
  __hip_bfloat16* wdt    = (__hip_bfloat16*)(ws + 119595008);     // 24,576
  float*          geff   = (float*)(ws + 119619584);              // 98,304
  float*          beff   = (float*)(ws + 119717888);              // 98,304

  prep_eff<<<(cB * cC + 255) / 256, 256, 0, stream>>>(norm_g, norm_b, dom_g, dom_b, rw, geff, beff);
  transpose_bf16<<<dim3(cHID / 64, cC / 64), 256, 0, stream>>>(fc1_w, fc1t, cC, cHID);
  build_fc2t<<<(cC * cKP + 255) / 256, 256, 0, stream>>>(fc2_w, w_up, fc2t);
  build_wdt<<<(32 * cC + 255) / 256, 256, 0, stream>>>(w_down, wdt);
  conv_dw<<<cB * cC / cPL, 128, 0, stream>>>(x, conv_w, conv_b, convb);
  ln_affine<<<cB * cH, 256, 0, stream>>>(convb, geff, beff, y);

  const int NTM = cMR / 128;  // 196
  for (int ch = 0; ch < cCH; ++ch) {
    const __hip_bfloat16* ych = y + (size_t)ch * cMR * cC;
    gemm_fc1<<<(cHID / 128) * NTM, 256, 0, stream>>>(fc1t, ych, fc1_b, h);
    lora_down<<<NTM, 256, 0, stream>>>(
        ych, wdt, tkp + (size_t)ch * cMR * 2, tki + (size_t)ch * cMR * 2, h);
    gemm_fc2o<<<NTM * (cC / 128), 256, 0, stream>>>(
        h, fc2t, fc2_b, gamma, x, out, ch * cMR);
  }
}

// Round 18
// 404.032 us; speedup vs baseline: 1.2021x; 1.2021x over previous
//
#include <hip/hip_runtime.h>
#include <hip/hip_bf16.h>
#include <cstdint>
#include <cstddef>

// Problem dims (fixed)
constexpr int cB   = 64;
constexpr int cC   = 384;
constexpr int cH   = 28;
constexpr int cW   = 28;
constexpr int cHID = 1536;
constexpr int cNTOK = cB * cH * cW;   // 50176
constexpr int cKP   = cHID + 32;      // padded h row: 1536 fc1 cols + 32 lora-z cols
constexpr int cCH   = 2;              // M chunks
constexpr int cMR   = cNTOK / cCH;    // 25088

typedef __attribute__((ext_vector_type(8))) short bf16x8;
typedef __attribute__((ext_vector_type(4))) float f32x4;

// tanh-form GELU (maps to v_exp_f32; |err| vs erf-gelu <= ~3e-3)
__device__ __forceinline__ float gelu_f(float x) {
  float u = 1.5957691216057308f * x * (1.0f + 0.044715f * x * x);
  float e = __expf(-u);
  return x / (1.0f + e);
}

__device__ __forceinline__ float bf16_to_f(unsigned short s) {
  return __uint_as_float(((unsigned)s) << 16);
}
__device__ __forceinline__ unsigned short f_to_bf16(float v) {
  __hip_bfloat16 hb = __float2bfloat16(v);
  return *reinterpret_cast<unsigned short*>(&hb);
}

__device__ __forceinline__ void gload_lds16(const void* g, void* l) {
  __builtin_amdgcn_global_load_lds(
      (const __attribute__((address_space(1))) unsigned int*)g,
      (__attribute__((address_space(3))) unsigned int*)l, 16, 0, 0);
}

// T1: bijective XCD-chunked block remap (m204).
__device__ __forceinline__ int xcd_remap(int b, int nwg) {
  int qn = nwg >> 3, rm = nwg & 7;
  int xcd = b & 7, off = b >> 3;
  return (xcd < rm) ? xcd * (qn + 1) + off
                    : rm * (qn + 1) + (xcd - rm) * qn + off;
}

// ---------------------------------------------------------------- prep ----
__global__ __launch_bounds__(256) void prep_eff(
    const float* __restrict__ ng, const float* __restrict__ nb,
    const float* __restrict__ dg, const float* __restrict__ db,
    const float* __restrict__ rw, float* __restrict__ geff, float* __restrict__ beff) {
  int i = blockIdx.x * 256 + threadIdx.x;  // b*C + c
  if (i >= cB * cC) return;
  int b = i / cC, c = i - b * cC;
  float g = ng[c], bb = nb[c];
#pragma unroll
  for (int e = 0; e < 3; ++e) {
    float r = rw[b * 3 + e];
    g += r * dg[e * cC + c];
    bb += r * db[e * cC + c];
  }
  geff[i] = g;
  beff[i] = bb;
}

// fc1_w [C][HID] f32 -> fc1t [HID][C] bf16, LDS-tiled 64x64.
__global__ __launch_bounds__(256) void transpose_bf16(
    const float* __restrict__ w, __hip_bfloat16* __restrict__ wt, int R0, int C0) {
  __shared__ float t[64][65];
  int c0 = blockIdx.x * 64, r0 = blockIdx.y * 64;
  for (int i = threadIdx.x; i < 64 * 64; i += 256) {
    int r = i >> 6, c = i & 63;
    t[r][c] = w[(size_t)(r0 + r) * C0 + c0 + c];
  }
  __syncthreads();
  for (int i = threadIdx.x; i < 64 * 64; i += 256) {
    int c = i >> 6, r = i & 63;
    wt[(size_t)(c0 + c) * R0 + r0 + r] = __float2bfloat16(t[r][c]);
  }
}

// fc2t [C=384][KP=1568]: k<1536 -> fc2_w[k][c]; 1536+j (j<24) -> wu[e][r][c]; else 0
__global__ __launch_bounds__(256) void build_fc2t(
    const float* __restrict__ fc2w, const float* __restrict__ wu,
    __hip_bfloat16* __restrict__ fc2t) {
  int i = blockIdx.x * 256 + threadIdx.x;  // c*KP + k
  if (i >= cC * cKP) return;
  int c = i / cKP, k = i - c * cKP;
  float v = 0.f;
  if (k < cHID) v = fc2w[(size_t)k * cC + c];
  else {
    int j = k - cHID;
    if (j < 24) v = wu[(size_t)(j >> 3) * 8 * cC + (size_t)(j & 7) * cC + c];
  }
  fc2t[i] = __float2bfloat16(v);
}

// wdt [32][C=384]: j<24 -> wd[e][c][r]; else 0   (wd layout [E][C][R])
__global__ __launch_bounds__(256) void build_wdt(
    const float* __restrict__ wd, __hip_bfloat16* __restrict__ wdt) {
  int i = blockIdx.x * 256 + threadIdx.x;  // j*C + c
  if (i >= 32 * cC) return;
  int j = i / cC, c = i - j * cC;
  float v = 0.f;
  if (j < 24) v = wd[(size_t)(j >> 3) * cC * 8 + (size_t)c * 8 + (j & 7)];
  wdt[i] = __float2bfloat16(v);
}

// ---------------------------------------------------- depthwise conv ----
// LDS-tiled, small blocks for overlap: 4 planes, 128 threads, 21.5KB LDS.
constexpr int cPL = 4;
__global__ __launch_bounds__(128) void conv_dw(
    const float* __restrict__ x, const float* __restrict__ cw,
    const float* __restrict__ cb, __hip_bfloat16* __restrict__ out) {
  int pb = blockIdx.x * cPL;  // first plane (b*C + c)
  int c0 = pb % cC;           // first channel
  __shared__ __align__(16) float tile[cPL][34][38];
  __shared__ float wsm[cPL][49];
  const int tid = threadIdx.x;

  float2 z2 = {0.f, 0.f};
  for (int i = tid; i < cPL * 34 * 19; i += 128)
    ((float2*)tile)[i] = z2;
  __syncthreads();

  for (int i = tid; i < cPL * 196; i += 128) {
    int p = i / 196, q = i - p * 196;
    int r = q / 7, cl = (q - r * 7) * 4;
    float4 v = *(const float4*)&x[(size_t)(pb + p) * 784 + r * 28 + cl];
    float* dst = &tile[p][r + 3][cl + 4];
    *(float2*)dst = make_float2(v.x, v.y);
    *(float2*)(dst + 2) = make_float2(v.z, v.w);
  }
  for (int i = tid; i < cPL * 49; i += 128) {
    int p = i / 49, k = i - p * 49;
    wsm[p][k] = cw[(size_t)(c0 + p) * 49 + k];
  }
  __syncthreads();

  if (tid < cPL * 28) {
    int p = tid / 28, r = tid - p * 28;
    float acc[28];
    float cbv = cb[c0 + p];
#pragma unroll
    for (int w = 0; w < 28; ++w) acc[w] = cbv;
    for (int dh = 0; dh < 7; ++dh) {
      float rowv[36];
      const float* rp = &tile[p][r + dh][0];
#pragma unroll
      for (int k = 0; k < 18; ++k)
        ((float2*)rowv)[k] = *(const float2*)(rp + k * 2);
      float w7[7];
#pragma unroll
      for (int dw = 0; dw < 7; ++dw) w7[dw] = wsm[p][dh * 7 + dw];
#pragma unroll
      for (int w = 0; w < 28; ++w)
#pragma unroll
        for (int dw = 0; dw < 7; ++dw)
          acc[w] += rowv[w + dw + 1] * w7[dw];
    }
    unsigned short* op = (unsigned short*)out + (size_t)(pb + p) * 784 + r * 28;
#pragma unroll
    for (int k = 0; k < 7; ++k) {
      ushort4 s;
      s.x = f_to_bf16(acc[k * 4 + 0]);
      s.y = f_to_bf16(acc[k * 4 + 1]);
      s.z = f_to_bf16(acc[k * 4 + 2]);
      s.w = f_to_bf16(acc[k * 4 + 3]);
      *(ushort4*)&op[k * 4] = s;
    }
  }
}

// ------------------------------------------- LayerNorm + affine -> bf16 ----
__global__ __launch_bounds__(256) void ln_affine(
    const __hip_bfloat16* __restrict__ convout, const float* __restrict__ geff,
    const float* __restrict__ beff, __hip_bfloat16* __restrict__ y) {
  int bh = blockIdx.x;            // b*H + h
  int b = bh / cH;
  int hrow = bh - b * cH;
  __shared__ float t[cC * 29];    // [c][w] padded to 29
  const unsigned short* src =
      (const unsigned short*)convout + (size_t)b * cC * (cH * cW) + (size_t)hrow * cW;
  for (int i = threadIdx.x; i < cC * 7; i += 256) {
    int c = i / 7, wq = (i - c * 7) * 4;
    ushort4 v = *(const ushort4*)&src[(size_t)c * (cH * cW) + wq];
    t[c * 29 + wq + 0] = bf16_to_f(v.x);
    t[c * 29 + wq + 1] = bf16_to_f(v.y);
    t[c * 29 + wq + 2] = bf16_to_f(v.z);
    t[c * 29 + wq + 3] = bf16_to_f(v.w);
  }
  __syncthreads();
  int wave = threadIdx.x >> 6, lane = threadIdx.x & 63;
  const float* gp = geff + (size_t)b * cC;
  const float* bp = beff + (size_t)b * cC;
  for (int w = wave; w < cW; w += 4) {
    float v[6], s = 0.f, s2 = 0.f;
#pragma unroll
    for (int j = 0; j < 6; ++j) {
      v[j] = t[(lane + 64 * j) * 29 + w];
      s += v[j];
      s2 += v[j] * v[j];
    }
#pragma unroll
    for (int d = 32; d; d >>= 1) {
      s += __shfl_xor(s, d);
      s2 += __shfl_xor(s2, d);
    }
    float mu = s * (1.0f / cC);
    float var = s2 * (1.0f / cC) - mu * mu;
    float rstd = rsqrtf(var + 1e-6f);
    size_t n = (size_t)bh * cW + w;
#pragma unroll
    for (int j = 0; j < 6; ++j) {
      int c = lane + 64 * j;
      float val = (v[j] - mu) * rstd * gp[c] + bp[c];
      y[n * cC + c] = __float2bfloat16(val);
    }
  }
}

// --------------------------------------------------------------- GEMM ----
// Cb[M,N](bf16, ldc) = A[M,K](lda) * Bt[N,K]^T + bias. Optional gelu.
// 128x128 tile, BK=32, 4 waves (2x2), 16x16x32 bf16 MFMA.
// Double-buffered global_load_lds (2-phase) + T1 XCD remap + supertile remap.
template <int DO_GELU>
__global__ __launch_bounds__(256) void gemm_bt(
    const __hip_bfloat16* __restrict__ A, int lda,
    const __hip_bfloat16* __restrict__ Bt,
    const float* __restrict__ bias,
    __hip_bfloat16* __restrict__ Cb, int ldc,
    int M, int N, int K, int NT_N) {
  __shared__ __align__(16) __hip_bfloat16 As[2][128 * 32];
  __shared__ __align__(16) __hip_bfloat16 Bs[2][128 * 32];

  const int bid = xcd_remap(blockIdx.x, gridDim.x);
  const int gsz = 8 * NT_N;
  const int g = bid / gsz;
  const int q = bid - g * gsz;
  const int mi = g * 8 + q / NT_N;
  const int ni = q - (q / NT_N) * NT_N;
  const int m0 = mi * 128, n0 = ni * 128;

  const int tid = threadIdx.x;
  const int lane = tid & 63;
  const int wid = tid >> 6;
  const int wm = wid >> 1, wn = wid & 1;

  const int base0 = wid * 2048;
  const int base1 = base0 + 1024;
  const int off0 = base0 + lane * 16, off1 = base1 + lane * 16;
  const int row0 = off0 >> 6, col0 = (off0 >> 1) & 31;
  const int row1 = off1 >> 6, col1 = (off1 >> 1) & 31;
  const __hip_bfloat16* pa0 = &A[(size_t)(m0 + row0) * lda + col0];
  const __hip_bfloat16* pa1 = &A[(size_t)(m0 + row1) * lda + col1];
  const __hip_bfloat16* pb0 = &Bt[(size_t)(n0 + row0) * K + col0];
  const __hip_bfloat16* pb1 = &Bt[(size_t)(n0 + row1) * K + col1];

  const int nt = K >> 5;

  gload_lds16(pa0, (char*)As[0] + base0);
  gload_lds16(pa1, (char*)As[0] + base1);
  gload_lds16(pb0, (char*)Bs[0] + base0);
  gload_lds16(pb1, (char*)Bs[0] + base1);
  pa0 += 32; pa1 += 32; pb0 += 32; pb1 += 32;
  __syncthreads();

  f32x4 acc[4][4] = {};
  int cur = 0;
  for (int t = 0; t < nt; ++t, cur ^= 1) {
    if (t + 1 < nt) {
      gload_lds16(pa0, (char*)As[cur ^ 1] + base0);
      gload_lds16(pa1, (char*)As[cur ^ 1] + base1);
      gload_lds16(pb0, (char*)Bs[cur ^ 1] + base0);
      gload_lds16(pb1, (char*)Bs[cur ^ 1] + base1);
      pa0 += 32; pa1 += 32; pb0 += 32; pb1 += 32;
    }
    bf16x8 af[4], bfr[4];
#pragma unroll
    for (int i = 0; i < 4; ++i)
      af[i] = *(const bf16x8*)&As[cur][(wm * 64 + i * 16 + (lane & 15)) * 32 + (lane >> 4) * 8];
#pragma unroll
    for (int i = 0; i < 4; ++i)
      bfr[i] = *(const bf16x8*)&Bs[cur][(wn * 64 + i * 16 + (lane & 15)) * 32 + (lane >> 4) * 8];
#pragma unroll
    for (int i = 0; i < 4; ++i)
#pragma unroll
      for (int j = 0; j < 4; ++j)
        acc[i][j] = __builtin_amdgcn_mfma_f32_16x16x32_bf16(af[i], bfr[j], acc[i][j], 0, 0, 0);
    __syncthreads();
  }

#pragma unroll
  for (int i = 0; i < 4; ++i) {
    int row = m0 + wm * 64 + i * 16 + (lane >> 4) * 4;
#pragma unroll
    for (int j = 0; j < 4; ++j) {
      int col = n0 + wn * 64 + j * 16 + (lane & 15);
      float bv = bias[col];
#pragma unroll
      for (int r = 0; r < 4; ++r) {
        float vv = acc[i][j][r] + bv;
        if (DO_GELU) vv = gelu_f(vv);
        Cb[(size_t)(row + r) * ldc + col] = __float2bfloat16(vv);
      }
    }
  }
}

// ----------------------------------------------------------- LoRA down ----
__global__ __launch_bounds__(256) void lora_down(
    const __hip_bfloat16* __restrict__ y,    // chunk base [MR][384]
    const __hip_bfloat16* __restrict__ wdt,  // [32][384]
    const float* __restrict__ probs,         // chunk base [MR][2]
    const int* __restrict__ inds,            // chunk base [MR][2]
    __hip_bfloat16* __restrict__ h) {        // chunk base [MR][cKP]
  __shared__ __align__(16) __hip_bfloat16 As[2][128 * 32];
  __shared__ __align__(16) __hip_bfloat16 Bsm[32 * 384];
  const int tid = threadIdx.x, lane = tid & 63, wid = tid >> 6;
  const int n0 = blockIdx.x * 128;

  for (int i = tid; i < 32 * 384 / 8; i += 256)
    ((bf16x8*)Bsm)[i] = ((const bf16x8*)wdt)[i];

  const int base0 = wid * 2048, base1 = base0 + 1024;
  const int off0 = base0 + lane * 16, off1 = base1 + lane * 16;
  const int row0 = off0 >> 6, col0 = (off0 >> 1) & 31;
  const int row1 = off1 >> 6, col1 = (off1 >> 1) & 31;
  const __hip_bfloat16* pa0 = &y[(size_t)(n0 + row0) * cC + col0];
  const __hip_bfloat16* pa1 = &y[(size_t)(n0 + row1) * cC + col1];

  const int nt = cC >> 5;  // 12
  gload_lds16(pa0, (char*)As[0] + base0);
  gload_lds16(pa1, (char*)As[0] + base1);
  pa0 += 32; pa1 += 32;
  __syncthreads();

  f32x4 acc[2][2] = {};
  int cur = 0;
  for (int t = 0; t < nt; ++t, cur ^= 1) {
    if (t + 1 < nt) {
      gload_lds16(pa0, (char*)As[cur ^ 1] + base0);
      gload_lds16(pa1, (char*)As[cur ^ 1] + base1);
      pa0 += 32; pa1 += 32;
    }
    int kt = t * 32;
    bf16x8 af[2], bfr[2];
#pragma unroll
    for (int i = 0; i < 2; ++i)
      af[i] = *(const bf16x8*)&As[cur][(wid * 32 + i * 16 + (lane & 15)) * 32 + (lane >> 4) * 8];
#pragma unroll
    for (int j = 0; j < 2; ++j)
      bfr[j] = *(const bf16x8*)&Bsm[(j * 16 + (lane & 15)) * 384 + kt + (lane >> 4) * 8];
#pragma unroll
    for (int i = 0; i < 2; ++i)
#pragma unroll
      for (int j = 0; j < 2; ++j)
        acc[i][j] = __builtin_amdgcn_mfma_f32_16x16x32_bf16(af[i], bfr[j], acc[i][j], 0, 0, 0);
    __syncthreads();
  }

#pragma unroll
  for (int i = 0; i < 2; ++i) {
#pragma unroll
    for (int j = 0; j < 2; ++j) {
      int colb = j * 16 + (lane & 15);
#pragma unroll
      for (int r = 0; r < 4; ++r) {
        int n = n0 + wid * 32 + i * 16 + (lane >> 4) * 4 + r;
        float zv = 0.f;
        if (colb < 24) {
          int e = colb >> 3;
          float comb = 0.f;
          if (inds[(size_t)n * 2] == e)     comb += probs[(size_t)n * 2];
          if (inds[(size_t)n * 2 + 1] == e) comb += probs[(size_t)n * 2 + 1];
          zv = comb * gelu_f(acc[i][j][r]);
        }
        h[(size_t)n * cKP + cHID + colb] = __float2bfloat16(zv);
      }
    }
  }
}

// ------------------------------------------------------------- epilogue ----
__global__ __launch_bounds__(256) void final_out(
    const __hip_bfloat16* __restrict__ tmp, const float* __restrict__ x,
    const float* __restrict__ gamma, float* __restrict__ out) {
  int bh = blockIdx.x;
  int b = bh / cH, hrow = bh - b * cH;
  __shared__ float t[cW * 385];  // [w][c] padded
  const __hip_bfloat16* src = tmp + (size_t)bh * cW * cC;
  for (int i = threadIdx.x; i < cW * cC / 8; i += 256) {
    bf16x8 v = ((const bf16x8*)src)[i];
    int base = i * 8;
    int w = base / cC, c = base - w * cC;
#pragma unroll
    for (int k = 0; k < 8; ++k)
      t[w * 385 + c + k] = bf16_to_f((unsigned short)v[k]);
  }
  __syncthreads();
  const float* xb = x + (size_t)b * cC * (cH * cW) + (size_t)hrow * cW;
  float* ob = out + (size_t)b * cC * (cH * cW) + (size_t)hrow * cW;
  for (int i = threadIdx.x; i < cC * cW; i += 256) {
    int c = i / cW, w = i - c * cW;
    ob[(size_t)c * (cH * cW) + w] = gamma[c] * t[w * 385 + c] + xb[(size_t)c * (cH * cW) + w];
  }
}

// ---------------------------------------------------------------------------
extern "C" void kernel_launch(void* const* d_in, const int* in_sizes, int n_in,
                              void* d_out, int out_size, void* d_ws, size_t ws_size,
                              hipStream_t stream) {
  const float* x      = (const float*)d_in[0];
  const float* conv_w = (const float*)d_in[1];
  const float* conv_b = (const float*)d_in[2];
  const float* norm_g = (const float*)d_in[3];
  const float* norm_b = (const float*)d_in[4];
  const float* dom_g  = (const float*)d_in[5];
  const float* dom_b  = (const float*)d_in[6];
  const float* fc1_w  = (const float*)d_in[7];
  const float* fc1_b  = (const float*)d_in[8];
  const float* fc2_w  = (const float*)d_in[9];
  const float* fc2_b  = (const float*)d_in[10];
  const float* w_down = (const float*)d_in[11];
  const float* w_up   = (const float*)d_in[12];
  const float* gamma  = (const float*)d_in[13];
  const float* rw     = (const float*)d_in[14];
  const float* tkp    = (const float*)d_in[15];
  const int*   tki    = (const int*)d_in[16];
  float* out = (float*)d_out;

  // ws layout (bytes); total ~160 MB
  char* ws = (char*)d_ws;
  __hip_bfloat16* y      = (__hip_bfloat16*)(ws + 0);             // 38,535,168
  __hip_bfloat16* tmpb   = (__hip_bfloat16*)(ws + 38535168);      // 38,535,168
  char*           hslot  = ws + 77070336;                         // 78,675,968
  __hip_bfloat16* h      = (__hip_bfloat16*)hslot;                // [MR][1568]
  __hip_bfloat16* convb  = (__hip_bfloat16*)hslot;                // conv buf (bf16)
  __hip_bfloat16* fc1t   = (__hip_bfloat16*)(ws + 155746304);     // 1,179,648
  __hip_bfloat16* fc2t   = (__hip_bfloat16*)(ws + 156925952);     // 1,204,224
  __hip_bfloat16* wdt    = (__hip_bfloat16*)(ws + 158130176);     // 24,576
  float*          geff   = (float*)(ws + 158154752);              // 98,304
  float*          beff   = (float*)(ws + 158253056);              // 98,304

  prep_eff<<<(cB * cC + 255) / 256, 256, 0, stream>>>(norm_g, norm_b, dom_g, dom_b, rw, geff, beff);
  transpose_bf16<<<dim3(cHID / 64, cC / 64), 256, 0, stream>>>(fc1_w, fc1t, cC, cHID);
  build_fc2t<<<(cC * cKP + 255) / 256, 256, 0, stream>>>(fc2_w, w_up, fc2t);
  build_wdt<<<(32 * cC + 255) / 256, 256, 0, stream>>>(w_down, wdt);
  conv_dw<<<cB * cC / cPL, 128, 0, stream>>>(x, conv_w, conv_b, convb);
  ln_affine<<<cB * cH, 256, 0, stream>>>(convb, geff, beff, y);

  const int NTM = cMR / 128;  // 196
  for (int ch = 0; ch < cCH; ++ch) {
    const __hip_bfloat16* ych = y + (size_t)ch * cMR * cC;
    gemm_bt<1><<<NTM * (cHID / 128), 256, 0, stream>>>(
        ych, cC, fc1t, fc1_b, h, cKP, cMR, cHID, cC, cHID / 128);
    lora_down<<<NTM, 256, 0, stream>>>(
        ych, wdt, tkp + (size_t)ch * cMR * 2, tki + (size_t)ch * cMR * 2, h);
    gemm_bt<0><<<NTM * (cC / 128), 256, 0, stream>>>(
        h, cKP, fc2t, fc2_b, tmpb + (size_t)ch * cMR * cC, cC, cMR, cC, cKP, cC / 128);
  }

  final_out<<<cB * cH, 256, 0, stream>>>(tmpb, x, gamma, out);
}